// Round 11
// baseline (371.065 us; speedup 1.0000x reference)
//
#include <hip/hip_runtime.h>

#define N_NODES 50000
#define E_EDGES 600000
#define LLM_DIM 640
#define HIDDEN 128
#define POUT 112
#define NB_SCAN 98        // ceil(50000/512)
#define FILL_BLOCKS 2344  // ceil(600000/256)
#define CONV_ELEMS (POUT * LLM_DIM + 2 * HIDDEN * HIDDEN)   // 104448
#define CONV_BLOCKS 408   // ceil(104448/256)
#define PZ_BLOCKS 196     // ceil(50000/256) -- pos zeroing
#define PROJ_BLOCKS 782   // ceil(50000/64)

typedef __attribute__((ext_vector_type(8))) short bf16x8;
typedef __attribute__((ext_vector_type(4))) float f32x4;

__device__ inline unsigned short f2bf(float f) {
    unsigned u = __float_as_uint(f);
    u += 0x7fff + ((u >> 16) & 1);   // RNE
    return (unsigned short)(u >> 16);
}
__device__ inline float bflo(unsigned v) { return __uint_as_float(v << 16); }
__device__ inline float bfhi(unsigned v) { return __uint_as_float(v & 0xffff0000u); }

// ---------------- deg_count + weight converts + pos zero (block-range split) ----------------
__global__ void deg_conv(const int* __restrict__ eidx, int* __restrict__ cnt,
                         const float* __restrict__ Wp, const float* __restrict__ Wg,
                         unsigned short* __restrict__ Wt, unsigned short* __restrict__ Wt2,
                         int* __restrict__ pos) {
    int b = blockIdx.x;
    if (b < FILL_BLOCKS) {
        int e = b * 256 + threadIdx.x;
        if (e < E_EDGES) atomicAdd(&cnt[eidx[E_EDGES + e]], 1);
    } else if (b < FILL_BLOCKS + CONV_BLOCKS) {
        int idx = (b - FILL_BLOCKS) * 256 + threadIdx.x;
        if (idx < POUT * LLM_DIM) {
            int n = idx / LLM_DIM;
            int k = idx - n * LLM_DIM;
            Wt[(size_t)n * LLM_DIM + k] = f2bf(Wp[(size_t)k * POUT + n]);
        } else if (idx < CONV_ELEMS) {
            int i2 = idx - POUT * LLM_DIM;
            int l = i2 >> 14;
            int rem = i2 & 16383;
            int n = rem >> 7;
            int k = rem & 127;
            Wt2[i2] = f2bf(Wg[l * 16384 + k * 128 + n]);
        }
    } else {
        int idx = (b - FILL_BLOCKS - CONV_BLOCKS) * 256 + threadIdx.x;
        if (idx < N_NODES) pos[idx] = 0;
    }
}

// ---------------- scan stage 1 (+ fused dis = rsqrt(1+deg)) ----------------
__global__ __launch_bounds__(256) void scan_blocksum(const int* __restrict__ cnt, int* __restrict__ bsum,
                                                     float* __restrict__ dis) {
    __shared__ int s[256];
    int b = blockIdx.x, t = threadIdx.x;
    int i0 = b * 512 + t, i1 = i0 + 256;
    int c0 = (i0 < N_NODES ? cnt[i0] : 0);
    int c1 = (i1 < N_NODES ? cnt[i1] : 0);
    if (i0 < N_NODES) dis[i0] = rsqrtf(1.0f + (float)c0);
    if (i1 < N_NODES) dis[i1] = rsqrtf(1.0f + (float)c1);
    s[t] = c0 + c1;
    __syncthreads();
    for (int st = 128; st; st >>= 1) {
        if (t < st) s[t] += s[t + st];
        __syncthreads();
    }
    if (t == 0) bsum[b] = s[0];
}

// ---------------- scan stage 2: per-chunk scan; block base computed in-kernel from bsum ----------------
// (folds the old scan_bsum launch: wave 0 reduces bsum[i < b] redundantly per block — ~98 loads)
__global__ __launch_bounds__(256) void scan_offs(const int* __restrict__ cnt, const int* __restrict__ bsum,
                                                 int* __restrict__ offs) {
    __shared__ int sA[512], sB[512];
    __shared__ int sbase;
    int b = blockIdx.x, t = threadIdx.x;
    if (t < 64) {
        int a = 0;
        if (t < b) a += bsum[t];
        if (t + 64 < b) a += bsum[t + 64];   // covers up to 128 >= NB_SCAN
#pragma unroll
        for (int off = 32; off; off >>= 1) a += __shfl_xor(a, off);
        if (t == 0) sbase = a;
    }
    int i0 = b * 512 + t, i1 = i0 + 256;
    int v0 = (i0 < N_NODES ? cnt[i0] : 0);
    int v1 = (i1 < N_NODES ? cnt[i1] : 0);
    sA[t] = v0; sA[t + 256] = v1;
    int* src = sA; int* dst = sB;
    for (int st = 1; st < 512; st <<= 1) {
        __syncthreads();
        dst[t]       = src[t]       + (t       >= st ? src[t - st]       : 0);
        dst[t + 256] = src[t + 256] + (t + 256 >= st ? src[t + 256 - st] : 0);
        int* tmp = src; src = dst; dst = tmp;
    }
    __syncthreads();
    int base = sbase;
    if (i0 < N_NODES) offs[i0] = base + src[t] - v0;
    if (i1 < N_NODES) offs[i1] = base + src[t + 256] - v1;
    if (b == 0 && t == 0) offs[N_NODES] = E_EDGES;
}

// ---------------- proj MFMA (K-chunk 128: 5 iters, half the barrier drains) + CSR fill ----------------
// Blocks [0, FILL_BLOCKS): fill_srcs. Blocks [FILL_BLOCKS, +PROJ_BLOCKS): proj.
// K=128 doubles bytes-in-flight per drain; MFMA accumulation order identical to K=64 (bit-exact).
// LDS = (64+112)*136*2 = 47872 B -> still 3 blocks/CU (grid-limited residency preserved).
__global__ __launch_bounds__(256) void proj_fill(const float* __restrict__ A,
                                                 const unsigned short* __restrict__ Wt,
                                                 const float* __restrict__ bias,
                                                 const float* __restrict__ emb,
                                                 const int* __restrict__ sid,
                                                 const float* __restrict__ dis,
                                                 unsigned short* __restrict__ Xs,
                                                 const int* __restrict__ eidx,
                                                 const int* __restrict__ offs,
                                                 int* __restrict__ pos,
                                                 int* __restrict__ srcs) {
    __shared__ short As[64][136];    // 64 x K128 + pad
    __shared__ short Bs[112][136];
    const int tid = threadIdx.x;

    if (blockIdx.x < FILL_BLOCKS) {
        int e = blockIdx.x * 256 + tid;
        if (e < E_EDGES) {
            int s = eidx[e];
            int d = eidx[E_EDGES + e];
            int p = atomicAdd(&pos[d], 1);
            srcs[offs[d] + p] = s;
        }
        return;
    }

    const int wave = tid >> 6, lane = tid & 63;
    const int row0 = (blockIdx.x - FILL_BLOCKS) * 64;
    const int l15 = lane & 15, l4 = lane >> 4;

    f32x4 acc[7];
#pragma unroll
    for (int j = 0; j < 7; j++) acc[j] = (f32x4){0.f, 0.f, 0.f, 0.f};

    for (int k0 = 0; k0 < LLM_DIM; k0 += 128) {
        // A tile 64x128 fp32 -> bf16 LDS. 2048 float4, 8/thread, coalesced per row.
#pragma unroll
        for (int i = 0; i < 8; i++) {
            int f = i * 256 + tid;
            int r = f >> 5;          // 32 float4 per row
            int q = f & 31;
            int grow = row0 + r;
            float4 v = make_float4(0.f, 0.f, 0.f, 0.f);
            if (grow < N_NODES)
                v = *reinterpret_cast<const float4*>(A + (size_t)grow * LLM_DIM + k0 + q * 4);
            uint2 u;
            u.x = (unsigned)f2bf(v.x) | ((unsigned)f2bf(v.y) << 16);
            u.y = (unsigned)f2bf(v.z) | ((unsigned)f2bf(v.w) << 16);
            *reinterpret_cast<uint2*>(&As[r][q * 4]) = u;
        }
        // B tile 112x128 bf16. 1792 uint4 (16B), 7/thread.
#pragma unroll
        for (int i = 0; i < 7; i++) {
            int f = i * 256 + tid;
            int n = f >> 4;          // 16 uint4 per row
            int q = f & 15;
            uint4 v = *reinterpret_cast<const uint4*>(Wt + (size_t)n * LLM_DIM + k0 + q * 8);
            *reinterpret_cast<uint4*>(&Bs[n][q * 8]) = v;
        }
        __syncthreads();
#pragma unroll
        for (int ks = 0; ks < 4; ks++) {
            int kk = ks * 32 + l4 * 8;
            bf16x8 a = *reinterpret_cast<bf16x8*>(&As[wave * 16 + l15][kk]);
#pragma unroll
            for (int ct = 0; ct < 7; ct++) {
                bf16x8 b = *reinterpret_cast<bf16x8*>(&Bs[ct * 16 + l15][kk]);
                acc[ct] = __builtin_amdgcn_mfma_f32_16x16x32_bf16(a, b, acc[ct], 0, 0, 0);
            }
        }
        __syncthreads();
    }
    // epilogue: rows row0 + wave*16 + l4*4 + r; cols ct*16 + l15 (+ emb cols 112..127)
#pragma unroll
    for (int r = 0; r < 4; r++) {
        int row = row0 + wave * 16 + l4 * 4 + r;
        if (row >= N_NODES) continue;
        float d = dis[row];
#pragma unroll
        for (int ct = 0; ct < 7; ct++) {
            int col = ct * 16 + l15;
            Xs[(size_t)row * HIDDEN + col] = f2bf(d * (acc[ct][r] + bias[col]));
        }
        float e = emb[sid[row] * 16 + l15];
        Xs[(size_t)row * HIDDEN + POUT + l15] = f2bf(d * e);
    }
}

// ---------------- CSR gather on bf16: Gb[i] = bf16(dis_i*(sum Xs[src] + Xs[i])) (proven) ----------------
__global__ __launch_bounds__(256) void gather(const unsigned short* __restrict__ Xs,
                                              const int* __restrict__ offs,
                                              const int* __restrict__ srcs,
                                              const float* __restrict__ dis,
                                              unsigned short* __restrict__ Gb) {
    int node = blockIdx.x * 4 + (threadIdx.x >> 6);
    int lane = threadIdx.x & 63;
    if (node >= N_NODES) return;
    int beg = __builtin_amdgcn_readfirstlane(offs[node]);
    int end = __builtin_amdgcn_readfirstlane(offs[node + 1]);
    const unsigned* X32 = reinterpret_cast<const unsigned*>(Xs);
    float d = dis[node];
    unsigned sv = X32[(size_t)node * 64 + lane];
    float ax = 0.f, ay = 0.f;
    int e = beg;
    while (e < end) {
        int n = end - e;
        if (n > 64) n = 64;
        int idx = (lane < n) ? srcs[e + lane] : 0;
        int j = 0;
        for (; j + 8 <= n; j += 8) {
            int s0 = __shfl(idx, j);
            int s1 = __shfl(idx, j + 1);
            int s2 = __shfl(idx, j + 2);
            int s3 = __shfl(idx, j + 3);
            int s4 = __shfl(idx, j + 4);
            int s5 = __shfl(idx, j + 5);
            int s6 = __shfl(idx, j + 6);
            int s7 = __shfl(idx, j + 7);
            unsigned v0 = X32[(size_t)s0 * 64 + lane];
            unsigned v1 = X32[(size_t)s1 * 64 + lane];
            unsigned v2 = X32[(size_t)s2 * 64 + lane];
            unsigned v3 = X32[(size_t)s3 * 64 + lane];
            unsigned v4 = X32[(size_t)s4 * 64 + lane];
            unsigned v5 = X32[(size_t)s5 * 64 + lane];
            unsigned v6 = X32[(size_t)s6 * 64 + lane];
            unsigned v7 = X32[(size_t)s7 * 64 + lane];
            ax += ((bflo(v0) + bflo(v1)) + (bflo(v2) + bflo(v3)))
                + ((bflo(v4) + bflo(v5)) + (bflo(v6) + bflo(v7)));
            ay += ((bfhi(v0) + bfhi(v1)) + (bfhi(v2) + bfhi(v3)))
                + ((bfhi(v4) + bfhi(v5)) + (bfhi(v6) + bfhi(v7)));
        }
        if (j + 4 <= n) {
            int s0 = __shfl(idx, j);
            int s1 = __shfl(idx, j + 1);
            int s2 = __shfl(idx, j + 2);
            int s3 = __shfl(idx, j + 3);
            unsigned v0 = X32[(size_t)s0 * 64 + lane];
            unsigned v1 = X32[(size_t)s1 * 64 + lane];
            unsigned v2 = X32[(size_t)s2 * 64 + lane];
            unsigned v3 = X32[(size_t)s3 * 64 + lane];
            ax += (bflo(v0) + bflo(v1)) + (bflo(v2) + bflo(v3));
            ay += (bfhi(v0) + bfhi(v1)) + (bfhi(v2) + bfhi(v3));
            j += 4;
        }
        int rem = n - j;
        if (rem > 0) {
            int s0 = __shfl(idx, j);
            int s1 = __shfl(idx, j + (rem > 1 ? 1 : 0));
            int s2 = __shfl(idx, j + (rem > 2 ? 2 : 0));
            unsigned v0 = X32[(size_t)s0 * 64 + lane];
            unsigned v1 = X32[(size_t)s1 * 64 + lane];
            unsigned v2 = X32[(size_t)s2 * 64 + lane];
            ax += bflo(v0) + (rem > 1 ? bflo(v1) : 0.f) + (rem > 2 ? bflo(v2) : 0.f);
            ay += bfhi(v0) + (rem > 1 ? bfhi(v1) : 0.f) + (rem > 2 ? bfhi(v2) : 0.f);
        }
        e += 64;
    }
    ax = d * (ax + bflo(sv));   // self term = dis_i * Xs_i
    ay = d * (ay + bfhi(sv));
    reinterpret_cast<unsigned*>(Gb)[(size_t)node * 64 + lane] =
        (unsigned)f2bf(ax) | ((unsigned)f2bf(ay) << 16);
}

// ---------------- fused GEMM + residual(+relu) in SCALED space (r8 proven) ----------------
// State carried only in Xs = bf16(d*x). vs = Xs + d*relu(Gb@W + b) == d*x_new (exact).
// MODE 0: XsOut = f2bf(vs). MODE 1: X = LayerNorm(vs, eps' = eps*d^2) == LN(x_new) exactly.
template <int MODE>
__global__ __launch_bounds__(256) void gemm_fin(const unsigned short* __restrict__ Gb,
                                                const unsigned short* __restrict__ Wt2,
                                                const float* __restrict__ bias,
                                                const float* __restrict__ dis,
                                                const float* __restrict__ lng,
                                                const float* __restrict__ lnb,
                                                const unsigned short* XsIn,
                                                float* __restrict__ X,
                                                unsigned short* XsOut) {
    __shared__ short As[64][136];    // K=128 + 8 pad
    __shared__ short Bs[128][136];
    const int tid = threadIdx.x;
    const int wave = tid >> 6, lane = tid & 63;
    const int row0 = blockIdx.x * 64;
    const int l15 = lane & 15, l4 = lane >> 4;

    // stage A 64x128 bf16: 1024 uint4, 4/thread
#pragma unroll
    for (int i = 0; i < 4; i++) {
        int f = i * 256 + tid;
        int r = f >> 4;
        int q = f & 15;
        int grow = row0 + r;
        uint4 v = make_uint4(0, 0, 0, 0);
        if (grow < N_NODES)
            v = reinterpret_cast<const uint4*>(Gb + (size_t)grow * HIDDEN)[q];
        *reinterpret_cast<uint4*>(&As[r][q * 8]) = v;
    }
    // stage B 128x128 bf16: 2048 uint4, 8/thread
#pragma unroll
    for (int i = 0; i < 8; i++) {
        int f = i * 256 + tid;
        int r = f >> 4;
        int q = f & 15;
        uint4 v = reinterpret_cast<const uint4*>(Wt2 + (size_t)r * HIDDEN)[q];
        *reinterpret_cast<uint4*>(&Bs[r][q * 8]) = v;
    }

    // hoisted residual (scaled space) + per-row dis; overlaps barrier + MFMA
    const unsigned* XsU = reinterpret_cast<const unsigned*>(XsIn);
    float xs[8][4];
    float dv[4];
#pragma unroll
    for (int r = 0; r < 4; r++) {
        int row = row0 + wave * 16 + l4 * 4 + r;
        int rc = row < N_NODES ? row : 0;
        dv[r] = dis[rc];
        bool hi = (l15 & 1) != 0;
#pragma unroll
        for (int ct = 0; ct < 8; ct++) {
            unsigned u = XsU[(size_t)rc * 64 + ct * 8 + (l15 >> 1)];
            xs[ct][r] = hi ? bfhi(u) : bflo(u);
        }
    }

    __syncthreads();

    f32x4 acc[8];
#pragma unroll
    for (int j = 0; j < 8; j++) acc[j] = (f32x4){0.f, 0.f, 0.f, 0.f};
#pragma unroll
    for (int ks = 0; ks < 4; ks++) {
        int kk = ks * 32 + l4 * 8;
        bf16x8 a = *reinterpret_cast<bf16x8*>(&As[wave * 16 + l15][kk]);
#pragma unroll
        for (int ct = 0; ct < 8; ct++) {
            bf16x8 b = *reinterpret_cast<bf16x8*>(&Bs[ct * 16 + l15][kk]);
            acc[ct] = __builtin_amdgcn_mfma_f32_16x16x32_bf16(a, b, acc[ct], 0, 0, 0);
        }
    }

    // epilogue: vs = xs + d*relu(acc + bias)   (== d * x_new, exact)
    float bcol[8];
#pragma unroll
    for (int ct = 0; ct < 8; ct++) bcol[ct] = bias[ct * 16 + l15];

    float vv[8][4];
#pragma unroll
    for (int r = 0; r < 4; r++) {
#pragma unroll
        for (int ct = 0; ct < 8; ct++)
            vv[ct][r] = xs[ct][r] + dv[r] * fmaxf(acc[ct][r] + bcol[ct], 0.f);
    }

    if (MODE == 0) {
#pragma unroll
        for (int r = 0; r < 4; r++) {
            int row = row0 + wave * 16 + l4 * 4 + r;
            if (row >= N_NODES) continue;
#pragma unroll
            for (int ct = 0; ct < 8; ct++)
                XsOut[(size_t)row * HIDDEN + ct * 16 + l15] = f2bf(vv[ct][r]);
        }
    } else {
        float s[4], q2[4];
#pragma unroll
        for (int r = 0; r < 4; r++) {
            s[r] = 0.f; q2[r] = 0.f;
#pragma unroll
            for (int ct = 0; ct < 8; ct++) {
                s[r] += vv[ct][r];
                q2[r] += vv[ct][r] * vv[ct][r];
            }
        }
#pragma unroll
        for (int off = 1; off < 16; off <<= 1) {
#pragma unroll
            for (int r = 0; r < 4; r++) {
                s[r] += __shfl_xor(s[r], off);
                q2[r] += __shfl_xor(q2[r], off);
            }
        }
        float gcol[8], bcol2[8];
#pragma unroll
        for (int ct = 0; ct < 8; ct++) {
            gcol[ct] = lng[ct * 16 + l15];
            bcol2[ct] = lnb[ct * 16 + l15];
        }
#pragma unroll
        for (int r = 0; r < 4; r++) {
            int row = row0 + wave * 16 + l4 * 4 + r;
            if (row >= N_NODES) continue;
            float mean = s[r] * (1.f / 128.f);
            float var = q2[r] * (1.f / 128.f) - mean * mean;
            float inv = rsqrtf(var + 1e-5f * dv[r] * dv[r]);   // eps scaled: LN exact in scaled space
#pragma unroll
            for (int ct = 0; ct < 8; ct++) {
                int col = ct * 16 + l15;
                X[(size_t)row * HIDDEN + col] = (vv[ct][r] - mean) * inv * gcol[ct] + bcol2[ct];
            }
        }
    }
}

extern "C" void kernel_launch(void* const* d_in, const int* in_sizes, int n_in,
                              void* d_out, int out_size, void* d_ws, size_t ws_size,
                              hipStream_t stream) {
    const float* llm   = (const float*)d_in[0];
    const int*   sid   = (const int*)d_in[1];
    const int*   eidx  = (const int*)d_in[2];
    const float* projW = (const float*)d_in[3];
    const float* projb = (const float*)d_in[4];
    const float* emb   = (const float*)d_in[5];
    const float* gcnW  = (const float*)d_in[6];
    const float* gcnb  = (const float*)d_in[7];
    const float* lng   = (const float*)d_in[8];
    const float* lnb   = (const float*)d_in[9];

    float* X = (float*)d_out;                                   // [N,128] fp32 (final only)
    unsigned short* Xs = (unsigned short*)d_ws;                 // [N,128] bf16 (running scaled state)
    unsigned short* Gb = Xs + (size_t)N_NODES * HIDDEN;         // [N,128] bf16
    unsigned short* Wt = Gb;                                    // [112,640] bf16 (overlaps Gb: dead before gather)
    unsigned short* Wt2 = Gb + (size_t)N_NODES * HIDDEN;        // [2,128,128] bf16
    float* dis = (float*)(Wt2 + 2 * HIDDEN * HIDDEN);           // [N]
    int* cnt  = (int*)(dis + N_NODES);                          // [N]
    int* pos  = cnt + N_NODES;                                  // [N] (zeroed in deg_conv tail blocks)
    int* offs = pos + N_NODES;                                  // [N+1]
    int* bsum = offs + N_NODES + 1;                             // [128]
    int* bpre = bsum + 128;                                     // [128] (unused; kept for layout stability)
    int* srcs = bpre + 128;                                     // [E]

    hipMemsetAsync(cnt, 0, N_NODES * sizeof(int), stream);      // cnt only (pos zeroed in deg_conv)
    deg_conv<<<FILL_BLOCKS + CONV_BLOCKS + PZ_BLOCKS, 256, 0, stream>>>(eidx, cnt, projW, gcnW,
                                                                        Wt, Wt2, pos);
    scan_blocksum<<<NB_SCAN, 256, 0, stream>>>(cnt, bsum, dis); // + fused make_dis
    scan_offs<<<NB_SCAN, 256, 0, stream>>>(cnt, bsum, offs);    // + in-kernel base (scan_bsum folded)

    // fill_srcs rides in the proj dispatch: fill blocks first (no-LDS, fast), proj blocks after
    proj_fill<<<FILL_BLOCKS + PROJ_BLOCKS, 256, 0, stream>>>(llm, Wt, projb, emb, sid, dis, Xs,
                                                             eidx, offs, pos, srcs);

    gather<<<(N_NODES + 3) / 4, 256, 0, stream>>>(Xs, offs, srcs, dis, Gb);
    gemm_fin<0><<<(N_NODES + 63) / 64, 256, 0, stream>>>(Gb, Wt2, gcnb, dis, lng, lnb, Xs, X, Xs);
    gather<<<(N_NODES + 3) / 4, 256, 0, stream>>>(Xs, offs, srcs, dis, Gb);
    gemm_fin<1><<<(N_NODES + 63) / 64, 256, 0, stream>>>(Gb, Wt2 + HIDDEN * HIDDEN, gcnb + HIDDEN,
                                                         dis, lng, lnb, Xs, X, Xs);
}

// Round 12
// 362.647 us; speedup vs baseline: 1.0232x; 1.0232x over previous
//
#include <hip/hip_runtime.h>

#define N_NODES 50000
#define E_EDGES 600000
#define LLM_DIM 640
#define HIDDEN 128
#define POUT 112
#define NB_SCAN 98        // ceil(50000/512)
#define FILL_BLOCKS 2344  // ceil(600000/256)
#define CONV_ELEMS (POUT * LLM_DIM + 2 * HIDDEN * HIDDEN)   // 104448
#define CONV_BLOCKS 408   // ceil(104448/256)
#define PZ_BLOCKS 196     // ceil(50000/256) -- pos zeroing
#define PROJ_BLOCKS 782   // ceil(50000/64)

typedef __attribute__((ext_vector_type(8))) short bf16x8;
typedef __attribute__((ext_vector_type(4))) float f32x4;

__device__ inline unsigned short f2bf(float f) {
    unsigned u = __float_as_uint(f);
    u += 0x7fff + ((u >> 16) & 1);   // RNE
    return (unsigned short)(u >> 16);
}
__device__ inline float bflo(unsigned v) { return __uint_as_float(v << 16); }
__device__ inline float bfhi(unsigned v) { return __uint_as_float(v & 0xffff0000u); }

// ---------------- deg_count + weight converts + pos zero (block-range split) ----------------
__global__ void deg_conv(const int* __restrict__ eidx, int* __restrict__ cnt,
                         const float* __restrict__ Wp, const float* __restrict__ Wg,
                         unsigned short* __restrict__ Wt, unsigned short* __restrict__ Wt2,
                         int* __restrict__ pos) {
    int b = blockIdx.x;
    if (b < FILL_BLOCKS) {
        int e = b * 256 + threadIdx.x;
        if (e < E_EDGES) atomicAdd(&cnt[eidx[E_EDGES + e]], 1);
    } else if (b < FILL_BLOCKS + CONV_BLOCKS) {
        int idx = (b - FILL_BLOCKS) * 256 + threadIdx.x;
        if (idx < POUT * LLM_DIM) {
            int n = idx / LLM_DIM;
            int k = idx - n * LLM_DIM;
            Wt[(size_t)n * LLM_DIM + k] = f2bf(Wp[(size_t)k * POUT + n]);
        } else if (idx < CONV_ELEMS) {
            int i2 = idx - POUT * LLM_DIM;
            int l = i2 >> 14;
            int rem = i2 & 16383;
            int n = rem >> 7;
            int k = rem & 127;
            Wt2[i2] = f2bf(Wg[l * 16384 + k * 128 + n]);
        }
    } else {
        int idx = (b - FILL_BLOCKS - CONV_BLOCKS) * 256 + threadIdx.x;
        if (idx < N_NODES) pos[idx] = 0;
    }
}

// ---------------- scan stage 1 (+ fused dis = rsqrt(1+deg)) ----------------
__global__ __launch_bounds__(256) void scan_blocksum(const int* __restrict__ cnt, int* __restrict__ bsum,
                                                     float* __restrict__ dis) {
    __shared__ int s[256];
    int b = blockIdx.x, t = threadIdx.x;
    int i0 = b * 512 + t, i1 = i0 + 256;
    int c0 = (i0 < N_NODES ? cnt[i0] : 0);
    int c1 = (i1 < N_NODES ? cnt[i1] : 0);
    if (i0 < N_NODES) dis[i0] = rsqrtf(1.0f + (float)c0);
    if (i1 < N_NODES) dis[i1] = rsqrtf(1.0f + (float)c1);
    s[t] = c0 + c1;
    __syncthreads();
    for (int st = 128; st; st >>= 1) {
        if (t < st) s[t] += s[t + st];
        __syncthreads();
    }
    if (t == 0) bsum[b] = s[0];
}

// ---------------- scan stage 2: per-chunk scan; block base computed in-kernel from bsum ----------------
__global__ __launch_bounds__(256) void scan_offs(const int* __restrict__ cnt, const int* __restrict__ bsum,
                                                 int* __restrict__ offs) {
    __shared__ int sA[512], sB[512];
    __shared__ int sbase;
    int b = blockIdx.x, t = threadIdx.x;
    if (t < 64) {
        int a = 0;
        if (t < b) a += bsum[t];
        if (t + 64 < b) a += bsum[t + 64];   // covers up to 128 >= NB_SCAN
#pragma unroll
        for (int off = 32; off; off >>= 1) a += __shfl_xor(a, off);
        if (t == 0) sbase = a;
    }
    int i0 = b * 512 + t, i1 = i0 + 256;
    int v0 = (i0 < N_NODES ? cnt[i0] : 0);
    int v1 = (i1 < N_NODES ? cnt[i1] : 0);
    sA[t] = v0; sA[t + 256] = v1;
    int* src = sA; int* dst = sB;
    for (int st = 1; st < 512; st <<= 1) {
        __syncthreads();
        dst[t]       = src[t]       + (t       >= st ? src[t - st]       : 0);
        dst[t + 256] = src[t + 256] + (t + 256 >= st ? src[t + 256 - st] : 0);
        int* tmp = src; src = dst; dst = tmp;
    }
    __syncthreads();
    int base = sbase;
    if (i0 < N_NODES) offs[i0] = base + src[t] - v0;
    if (i1 < N_NODES) offs[i1] = base + src[t + 256] - v1;
    if (b == 0 && t == 0) offs[N_NODES] = E_EDGES;
}

// ---------------- proj MFMA (K=64, r10-proven loop) + CSR fill + COALESCED Xs epilogue ----------------
// Blocks [0, FILL_BLOCKS): fill_srcs. Blocks after: proj.
// Epilogue fix: 2B/lane scattered Xs stores caused ~3x write amplification (WRITE_SIZE 51.9MB vs
// ~15 ideal; 32B segments -> sector RMW). Now bf16 results are re-packed through the dead LDS
// tile after the K-loop and dumped as row-contiguous uint4 (16B/lane, 256B/row segments).
__global__ __launch_bounds__(256) void proj_fill(const float* __restrict__ A,
                                                 const unsigned short* __restrict__ Wt,
                                                 const float* __restrict__ bias,
                                                 const float* __restrict__ emb,
                                                 const int* __restrict__ sid,
                                                 const float* __restrict__ dis,
                                                 unsigned short* __restrict__ Xs,
                                                 const int* __restrict__ eidx,
                                                 const int* __restrict__ offs,
                                                 int* __restrict__ pos,
                                                 int* __restrict__ srcs) {
    __shared__ __align__(16) short Smem[64 * 72 + 112 * 72];   // As | Bs; reused as Xt[64][128]
    short (*As)[72] = reinterpret_cast<short(*)[72]>(Smem);
    short (*Bs)[72] = reinterpret_cast<short(*)[72]>(Smem + 64 * 72);
    const int tid = threadIdx.x;

    if (blockIdx.x < FILL_BLOCKS) {
        int e = blockIdx.x * 256 + tid;
        if (e < E_EDGES) {
            int s = eidx[e];
            int d = eidx[E_EDGES + e];
            int p = atomicAdd(&pos[d], 1);
            srcs[offs[d] + p] = s;
        }
        return;
    }

    const int wave = tid >> 6, lane = tid & 63;
    const int row0 = (blockIdx.x - FILL_BLOCKS) * 64;
    const int l15 = lane & 15, l4 = lane >> 4;

    f32x4 acc[7];
#pragma unroll
    for (int j = 0; j < 7; j++) acc[j] = (f32x4){0.f, 0.f, 0.f, 0.f};

    for (int k0 = 0; k0 < LLM_DIM; k0 += 64) {
        // A tile 64x64 fp32 -> bf16 LDS. 1024 float4, 4/thread, coalesced per row.
#pragma unroll
        for (int i = 0; i < 4; i++) {
            int f = i * 256 + tid;
            int r = f >> 4;          // 16 float4 per row
            int q = f & 15;
            int grow = row0 + r;
            float4 v = make_float4(0.f, 0.f, 0.f, 0.f);
            if (grow < N_NODES)
                v = *reinterpret_cast<const float4*>(A + (size_t)grow * LLM_DIM + k0 + q * 4);
            uint2 u;
            u.x = (unsigned)f2bf(v.x) | ((unsigned)f2bf(v.y) << 16);
            u.y = (unsigned)f2bf(v.z) | ((unsigned)f2bf(v.w) << 16);
            *reinterpret_cast<uint2*>(&As[r][q * 4]) = u;
        }
        // B tile 112x64 bf16. 1792 8B chunks, 7/thread.
#pragma unroll
        for (int i = 0; i < 7; i++) {
            int f = i * 256 + tid;
            int n = f >> 4;
            int q = f & 15;
            uint2 v = *reinterpret_cast<const uint2*>(Wt + (size_t)n * LLM_DIM + k0 + q * 4);
            *reinterpret_cast<uint2*>(&Bs[n][q * 4]) = v;
        }
        __syncthreads();
#pragma unroll
        for (int ks = 0; ks < 2; ks++) {
            int kk = ks * 32 + l4 * 8;
            bf16x8 a = *reinterpret_cast<bf16x8*>(&As[wave * 16 + l15][kk]);
#pragma unroll
            for (int ct = 0; ct < 7; ct++) {
                bf16x8 b = *reinterpret_cast<bf16x8*>(&Bs[ct * 16 + l15][kk]);
                acc[ct] = __builtin_amdgcn_mfma_f32_16x16x32_bf16(a, b, acc[ct], 0, 0, 0);
            }
        }
        __syncthreads();   // last iter: also releases Smem for epilogue reuse
    }

    // ---- epilogue: pack bf16(d*(acc+bias)) + emb into LDS Xt[64][128], then coalesced dump ----
    unsigned short* Xt = reinterpret_cast<unsigned short*>(Smem);
#pragma unroll
    for (int r = 0; r < 4; r++) {
        int rl = wave * 16 + l4 * 4 + r;          // local row 0..63
        int row = row0 + rl;
        float d = (row < N_NODES) ? dis[row] : 0.f;
#pragma unroll
        for (int ct = 0; ct < 7; ct++) {
            int col = ct * 16 + l15;
            Xt[rl * HIDDEN + col] = f2bf(d * (acc[ct][r] + bias[col]));
        }
        unsigned short ev = 0;
        if (row < N_NODES) ev = f2bf(d * emb[sid[row] * 16 + l15]);
        Xt[rl * HIDDEN + POUT + l15] = ev;
    }
    __syncthreads();
#pragma unroll
    for (int i = 0; i < 4; i++) {
        int f = i * 256 + tid;
        int r = f >> 4;          // 16 uint4 per 256B row
        int q = f & 15;
        int grow = row0 + r;
        if (grow < N_NODES)
            reinterpret_cast<uint4*>(Xs + (size_t)grow * HIDDEN)[q] =
                *reinterpret_cast<const uint4*>(&Xt[r * HIDDEN + q * 8]);
    }
}

// ---------------- CSR gather on bf16: Gb[i] = bf16(dis_i*(sum Xs[src] + Xs[i])) (proven) ----------------
__global__ __launch_bounds__(256) void gather(const unsigned short* __restrict__ Xs,
                                              const int* __restrict__ offs,
                                              const int* __restrict__ srcs,
                                              const float* __restrict__ dis,
                                              unsigned short* __restrict__ Gb) {
    int node = blockIdx.x * 4 + (threadIdx.x >> 6);
    int lane = threadIdx.x & 63;
    if (node >= N_NODES) return;
    int beg = __builtin_amdgcn_readfirstlane(offs[node]);
    int end = __builtin_amdgcn_readfirstlane(offs[node + 1]);
    const unsigned* X32 = reinterpret_cast<const unsigned*>(Xs);
    float d = dis[node];
    unsigned sv = X32[(size_t)node * 64 + lane];
    float ax = 0.f, ay = 0.f;
    int e = beg;
    while (e < end) {
        int n = end - e;
        if (n > 64) n = 64;
        int idx = (lane < n) ? srcs[e + lane] : 0;
        int j = 0;
        for (; j + 8 <= n; j += 8) {
            int s0 = __shfl(idx, j);
            int s1 = __shfl(idx, j + 1);
            int s2 = __shfl(idx, j + 2);
            int s3 = __shfl(idx, j + 3);
            int s4 = __shfl(idx, j + 4);
            int s5 = __shfl(idx, j + 5);
            int s6 = __shfl(idx, j + 6);
            int s7 = __shfl(idx, j + 7);
            unsigned v0 = X32[(size_t)s0 * 64 + lane];
            unsigned v1 = X32[(size_t)s1 * 64 + lane];
            unsigned v2 = X32[(size_t)s2 * 64 + lane];
            unsigned v3 = X32[(size_t)s3 * 64 + lane];
            unsigned v4 = X32[(size_t)s4 * 64 + lane];
            unsigned v5 = X32[(size_t)s5 * 64 + lane];
            unsigned v6 = X32[(size_t)s6 * 64 + lane];
            unsigned v7 = X32[(size_t)s7 * 64 + lane];
            ax += ((bflo(v0) + bflo(v1)) + (bflo(v2) + bflo(v3)))
                + ((bflo(v4) + bflo(v5)) + (bflo(v6) + bflo(v7)));
            ay += ((bfhi(v0) + bfhi(v1)) + (bfhi(v2) + bfhi(v3)))
                + ((bfhi(v4) + bfhi(v5)) + (bfhi(v6) + bfhi(v7)));
        }
        if (j + 4 <= n) {
            int s0 = __shfl(idx, j);
            int s1 = __shfl(idx, j + 1);
            int s2 = __shfl(idx, j + 2);
            int s3 = __shfl(idx, j + 3);
            unsigned v0 = X32[(size_t)s0 * 64 + lane];
            unsigned v1 = X32[(size_t)s1 * 64 + lane];
            unsigned v2 = X32[(size_t)s2 * 64 + lane];
            unsigned v3 = X32[(size_t)s3 * 64 + lane];
            ax += (bflo(v0) + bflo(v1)) + (bflo(v2) + bflo(v3));
            ay += (bfhi(v0) + bfhi(v1)) + (bfhi(v2) + bfhi(v3));
            j += 4;
        }
        int rem = n - j;
        if (rem > 0) {
            int s0 = __shfl(idx, j);
            int s1 = __shfl(idx, j + (rem > 1 ? 1 : 0));
            int s2 = __shfl(idx, j + (rem > 2 ? 2 : 0));
            unsigned v0 = X32[(size_t)s0 * 64 + lane];
            unsigned v1 = X32[(size_t)s1 * 64 + lane];
            unsigned v2 = X32[(size_t)s2 * 64 + lane];
            ax += bflo(v0) + (rem > 1 ? bflo(v1) : 0.f) + (rem > 2 ? bflo(v2) : 0.f);
            ay += bfhi(v0) + (rem > 1 ? bfhi(v1) : 0.f) + (rem > 2 ? bfhi(v2) : 0.f);
        }
        e += 64;
    }
    ax = d * (ax + bflo(sv));   // self term = dis_i * Xs_i
    ay = d * (ay + bfhi(sv));
    reinterpret_cast<unsigned*>(Gb)[(size_t)node * 64 + lane] =
        (unsigned)f2bf(ax) | ((unsigned)f2bf(ay) << 16);
}

// ---------------- fused GEMM + residual(+relu) in SCALED space; MODE 0 uses coalesced dump ----------------
// MODE 0: XsOut = f2bf(vs) via LDS repack (same write-amplification fix as proj).
// MODE 1: X = LayerNorm(vs, eps' = eps*d^2) == LN(x_new) exactly (fp32 64B-segment stores, left as is).
template <int MODE>
__global__ __launch_bounds__(256) void gemm_fin(const unsigned short* __restrict__ Gb,
                                                const unsigned short* __restrict__ Wt2,
                                                const float* __restrict__ bias,
                                                const float* __restrict__ dis,
                                                const float* __restrict__ lng,
                                                const float* __restrict__ lnb,
                                                const unsigned short* XsIn,
                                                float* __restrict__ X,
                                                unsigned short* XsOut) {
    __shared__ __align__(16) short Smem[64 * 136 + 128 * 136];   // As | Bs; reused as Xt[64][128]
    short (*As)[136] = reinterpret_cast<short(*)[136]>(Smem);
    short (*Bs)[136] = reinterpret_cast<short(*)[136]>(Smem + 64 * 136);
    const int tid = threadIdx.x;
    const int wave = tid >> 6, lane = tid & 63;
    const int row0 = blockIdx.x * 64;
    const int l15 = lane & 15, l4 = lane >> 4;

    // stage A 64x128 bf16: 1024 uint4, 4/thread
#pragma unroll
    for (int i = 0; i < 4; i++) {
        int f = i * 256 + tid;
        int r = f >> 4;
        int q = f & 15;
        int grow = row0 + r;
        uint4 v = make_uint4(0, 0, 0, 0);
        if (grow < N_NODES)
            v = reinterpret_cast<const uint4*>(Gb + (size_t)grow * HIDDEN)[q];
        *reinterpret_cast<uint4*>(&As[r][q * 8]) = v;
    }
    // stage B 128x128 bf16: 2048 uint4, 8/thread
#pragma unroll
    for (int i = 0; i < 8; i++) {
        int f = i * 256 + tid;
        int r = f >> 4;
        int q = f & 15;
        uint4 v = reinterpret_cast<const uint4*>(Wt2 + (size_t)r * HIDDEN)[q];
        *reinterpret_cast<uint4*>(&Bs[r][q * 8]) = v;
    }

    // hoisted residual (scaled space) + per-row dis; overlaps barrier + MFMA
    const unsigned* XsU = reinterpret_cast<const unsigned*>(XsIn);
    float xs[8][4];
    float dv[4];
#pragma unroll
    for (int r = 0; r < 4; r++) {
        int row = row0 + wave * 16 + l4 * 4 + r;
        int rc = row < N_NODES ? row : 0;
        dv[r] = dis[rc];
        bool hi = (l15 & 1) != 0;
#pragma unroll
        for (int ct = 0; ct < 8; ct++) {
            unsigned u = XsU[(size_t)rc * 64 + ct * 8 + (l15 >> 1)];
            xs[ct][r] = hi ? bfhi(u) : bflo(u);
        }
    }

    __syncthreads();

    f32x4 acc[8];
#pragma unroll
    for (int j = 0; j < 8; j++) acc[j] = (f32x4){0.f, 0.f, 0.f, 0.f};
#pragma unroll
    for (int ks = 0; ks < 4; ks++) {
        int kk = ks * 32 + l4 * 8;
        bf16x8 a = *reinterpret_cast<bf16x8*>(&As[wave * 16 + l15][kk]);
#pragma unroll
        for (int ct = 0; ct < 8; ct++) {
            bf16x8 b = *reinterpret_cast<bf16x8*>(&Bs[ct * 16 + l15][kk]);
            acc[ct] = __builtin_amdgcn_mfma_f32_16x16x32_bf16(a, b, acc[ct], 0, 0, 0);
        }
    }

    // epilogue: vs = xs + d*relu(acc + bias)   (== d * x_new, exact)
    float bcol[8];
#pragma unroll
    for (int ct = 0; ct < 8; ct++) bcol[ct] = bias[ct * 16 + l15];

    float vv[8][4];
#pragma unroll
    for (int r = 0; r < 4; r++) {
#pragma unroll
        for (int ct = 0; ct < 8; ct++)
            vv[ct][r] = xs[ct][r] + dv[r] * fmaxf(acc[ct][r] + bcol[ct], 0.f);
    }

    if (MODE == 0) {
        __syncthreads();   // all MFMA reads of As/Bs done -> reuse Smem
        unsigned short* Xt = reinterpret_cast<unsigned short*>(Smem);
#pragma unroll
        for (int r = 0; r < 4; r++) {
            int rl = wave * 16 + l4 * 4 + r;
#pragma unroll
            for (int ct = 0; ct < 8; ct++)
                Xt[rl * HIDDEN + ct * 16 + l15] = f2bf(vv[ct][r]);
        }
        __syncthreads();
#pragma unroll
        for (int i = 0; i < 4; i++) {
            int f = i * 256 + tid;
            int r = f >> 4;
            int q = f & 15;
            int grow = row0 + r;
            if (grow < N_NODES)
                reinterpret_cast<uint4*>(XsOut + (size_t)grow * HIDDEN)[q] =
                    *reinterpret_cast<const uint4*>(&Xt[r * HIDDEN + q * 8]);
        }
    } else {
        float s[4], q2[4];
#pragma unroll
        for (int r = 0; r < 4; r++) {
            s[r] = 0.f; q2[r] = 0.f;
#pragma unroll
            for (int ct = 0; ct < 8; ct++) {
                s[r] += vv[ct][r];
                q2[r] += vv[ct][r] * vv[ct][r];
            }
        }
#pragma unroll
        for (int off = 1; off < 16; off <<= 1) {
#pragma unroll
            for (int r = 0; r < 4; r++) {
                s[r] += __shfl_xor(s[r], off);
                q2[r] += __shfl_xor(q2[r], off);
            }
        }
        float gcol[8], bcol2[8];
#pragma unroll
        for (int ct = 0; ct < 8; ct++) {
            gcol[ct] = lng[ct * 16 + l15];
            bcol2[ct] = lnb[ct * 16 + l15];
        }
#pragma unroll
        for (int r = 0; r < 4; r++) {
            int row = row0 + wave * 16 + l4 * 4 + r;
            if (row >= N_NODES) continue;
            float mean = s[r] * (1.f / 128.f);
            float var = q2[r] * (1.f / 128.f) - mean * mean;
            float inv = rsqrtf(var + 1e-5f * dv[r] * dv[r]);   // eps scaled: LN exact in scaled space
#pragma unroll
            for (int ct = 0; ct < 8; ct++) {
                int col = ct * 16 + l15;
                X[(size_t)row * HIDDEN + col] = (vv[ct][r] - mean) * inv * gcol[ct] + bcol2[ct];
            }
        }
    }
}

extern "C" void kernel_launch(void* const* d_in, const int* in_sizes, int n_in,
                              void* d_out, int out_size, void* d_ws, size_t ws_size,
                              hipStream_t stream) {
    const float* llm   = (const float*)d_in[0];
    const int*   sid   = (const int*)d_in[1];
    const int*   eidx  = (const int*)d_in[2];
    const float* projW = (const float*)d_in[3];
    const float* projb = (const float*)d_in[4];
    const float* emb   = (const float*)d_in[5];
    const float* gcnW  = (const float*)d_in[6];
    const float* gcnb  = (const float*)d_in[7];
    const float* lng   = (const float*)d_in[8];
    const float* lnb   = (const float*)d_in[9];

    float* X = (float*)d_out;                                   // [N,128] fp32 (final only)
    unsigned short* Xs = (unsigned short*)d_ws;                 // [N,128] bf16 (running scaled state)
    unsigned short* Gb = Xs + (size_t)N_NODES * HIDDEN;         // [N,128] bf16
    unsigned short* Wt = Gb;                                    // [112,640] bf16 (overlaps Gb: dead before gather)
    unsigned short* Wt2 = Gb + (size_t)N_NODES * HIDDEN;        // [2,128,128] bf16
    float* dis = (float*)(Wt2 + 2 * HIDDEN * HIDDEN);           // [N]
    int* cnt  = (int*)(dis + N_NODES);                          // [N]
    int* pos  = cnt + N_NODES;                                  // [N] (zeroed in deg_conv tail blocks)
    int* offs = pos + N_NODES;                                  // [N+1]
    int* bsum = offs + N_NODES + 1;                             // [128]
    int* bpre = bsum + 128;                                     // [128] (unused; layout stability)
    int* srcs = bpre + 128;                                     // [E]

    hipMemsetAsync(cnt, 0, N_NODES * sizeof(int), stream);      // cnt only (pos zeroed in deg_conv)
    deg_conv<<<FILL_BLOCKS + CONV_BLOCKS + PZ_BLOCKS, 256, 0, stream>>>(eidx, cnt, projW, gcnW,
                                                                        Wt, Wt2, pos);
    scan_blocksum<<<NB_SCAN, 256, 0, stream>>>(cnt, bsum, dis); // + fused make_dis
    scan_offs<<<NB_SCAN, 256, 0, stream>>>(cnt, bsum, offs);    // + in-kernel base (scan_bsum folded)

    // fill_srcs rides in the proj dispatch: fill blocks first (no-LDS, fast), proj blocks after
    proj_fill<<<FILL_BLOCKS + PROJ_BLOCKS, 256, 0, stream>>>(llm, Wt, projb, emb, sid, dis, Xs,
                                                             eidx, offs, pos, srcs);

    gather<<<(N_NODES + 3) / 4, 256, 0, stream>>>(Xs, offs, srcs, dis, Gb);
    gemm_fin<0><<<(N_NODES + 63) / 64, 256, 0, stream>>>(Gb, Wt2, gcnb, dis, lng, lnb, Xs, X, Xs);
    gather<<<(N_NODES + 3) / 4, 256, 0, stream>>>(Xs, offs, srcs, dis, Gb);
    gemm_fin<1><<<(N_NODES + 63) / 64, 256, 0, stream>>>(Gb, Wt2 + HIDDEN * HIDDEN, gcnb + HIDDEN,
                                                         dis, lng, lnb, Xs, X, Xs);
}

// Round 13
// 349.865 us; speedup vs baseline: 1.0606x; 1.0365x over previous
//
#include <hip/hip_runtime.h>

#define N_NODES 50000
#define E_EDGES 600000
#define LLM_DIM 640
#define HIDDEN 128
#define POUT 112
#define NB_SCAN 98        // ceil(50000/512)
#define FILL_BLOCKS 2344  // ceil(600000/256)
#define CONV_ELEMS (POUT * LLM_DIM + 2 * HIDDEN * HIDDEN)   // 104448
#define CONV_BLOCKS 408   // ceil(104448/256)
#define PZ_BLOCKS 196     // ceil(50000/256) -- pos zeroing
#define PROJ_BLOCKS 782   // ceil(50000/64)

typedef __attribute__((ext_vector_type(8))) short bf16x8;
typedef __attribute__((ext_vector_type(4))) float f32x4;

__device__ inline unsigned short f2bf(float f) {
    unsigned u = __float_as_uint(f);
    u += 0x7fff + ((u >> 16) & 1);   // RNE
    return (unsigned short)(u >> 16);
}
__device__ inline float bflo(unsigned v) { return __uint_as_float(v << 16); }
__device__ inline float bfhi(unsigned v) { return __uint_as_float(v & 0xffff0000u); }

// ---------------- deg_count + weight converts + pos zero (block-range split) ----------------
__global__ void deg_conv(const int* __restrict__ eidx, int* __restrict__ cnt,
                         const float* __restrict__ Wp, const float* __restrict__ Wg,
                         unsigned short* __restrict__ Wt, unsigned short* __restrict__ Wt2,
                         int* __restrict__ pos) {
    int b = blockIdx.x;
    if (b < FILL_BLOCKS) {
        int e = b * 256 + threadIdx.x;
        if (e < E_EDGES) atomicAdd(&cnt[eidx[E_EDGES + e]], 1);
    } else if (b < FILL_BLOCKS + CONV_BLOCKS) {
        int idx = (b - FILL_BLOCKS) * 256 + threadIdx.x;
        if (idx < POUT * LLM_DIM) {
            int n = idx / LLM_DIM;
            int k = idx - n * LLM_DIM;
            Wt[(size_t)n * LLM_DIM + k] = f2bf(Wp[(size_t)k * POUT + n]);
        } else if (idx < CONV_ELEMS) {
            int i2 = idx - POUT * LLM_DIM;
            int l = i2 >> 14;
            int rem = i2 & 16383;
            int n = rem >> 7;
            int k = rem & 127;
            Wt2[i2] = f2bf(Wg[l * 16384 + k * 128 + n]);
        }
    } else {
        int idx = (b - FILL_BLOCKS - CONV_BLOCKS) * 256 + threadIdx.x;
        if (idx < N_NODES) pos[idx] = 0;
    }
}

// ---------------- scan stage 1 (+ fused dis = rsqrt(1+deg)) ----------------
__global__ __launch_bounds__(256) void scan_blocksum(const int* __restrict__ cnt, int* __restrict__ bsum,
                                                     float* __restrict__ dis) {
    __shared__ int s[256];
    int b = blockIdx.x, t = threadIdx.x;
    int i0 = b * 512 + t, i1 = i0 + 256;
    int c0 = (i0 < N_NODES ? cnt[i0] : 0);
    int c1 = (i1 < N_NODES ? cnt[i1] : 0);
    if (i0 < N_NODES) dis[i0] = rsqrtf(1.0f + (float)c0);
    if (i1 < N_NODES) dis[i1] = rsqrtf(1.0f + (float)c1);
    s[t] = c0 + c1;
    __syncthreads();
    for (int st = 128; st; st >>= 1) {
        if (t < st) s[t] += s[t + st];
        __syncthreads();
    }
    if (t == 0) bsum[b] = s[0];
}

// ---------------- scan stage 2: per-chunk scan; block base computed in-kernel from bsum ----------------
__global__ __launch_bounds__(256) void scan_offs(const int* __restrict__ cnt, const int* __restrict__ bsum,
                                                 int* __restrict__ offs) {
    __shared__ int sA[512], sB[512];
    __shared__ int sbase;
    int b = blockIdx.x, t = threadIdx.x;
    if (t < 64) {
        int a = 0;
        if (t < b) a += bsum[t];
        if (t + 64 < b) a += bsum[t + 64];   // covers up to 128 >= NB_SCAN
#pragma unroll
        for (int off = 32; off; off >>= 1) a += __shfl_xor(a, off);
        if (t == 0) sbase = a;
    }
    int i0 = b * 512 + t, i1 = i0 + 256;
    int v0 = (i0 < N_NODES ? cnt[i0] : 0);
    int v1 = (i1 < N_NODES ? cnt[i1] : 0);
    sA[t] = v0; sA[t + 256] = v1;
    int* src = sA; int* dst = sB;
    for (int st = 1; st < 512; st <<= 1) {
        __syncthreads();
        dst[t]       = src[t]       + (t       >= st ? src[t - st]       : 0);
        dst[t + 256] = src[t + 256] + (t + 256 >= st ? src[t + 256 - st] : 0);
        int* tmp = src; src = dst; dst = tmp;
    }
    __syncthreads();
    int base = sbase;
    if (i0 < N_NODES) offs[i0] = base + src[t] - v0;
    if (i1 < N_NODES) offs[i1] = base + src[t + 256] - v1;
    if (b == 0 && t == 0) offs[N_NODES] = E_EDGES;
}

// ---------------- proj MFMA (r10-proven K=64 loop) FIRST + CSR fill blocks AFTER ----------------
// Block order swapped vs r10: proj blocks [0, PROJ_BLOCKS) launch first and occupy every CU at
// t=0; fill blocks ride in the remaining resident slots (25.6KB LDS -> 6 blocks/CU, 1536
// resident > 782 proj). Fill's latency-bound atomics overlap proj's barrier-bound MFMA loop
// instead of serializing in front of it (r10: 103.6us = fill ~26 + proj ~77, no overlap).
__global__ __launch_bounds__(256) void proj_fill(const float* __restrict__ A,
                                                 const unsigned short* __restrict__ Wt,
                                                 const float* __restrict__ bias,
                                                 const float* __restrict__ emb,
                                                 const int* __restrict__ sid,
                                                 const float* __restrict__ dis,
                                                 unsigned short* __restrict__ Xs,
                                                 const int* __restrict__ eidx,
                                                 const int* __restrict__ offs,
                                                 int* __restrict__ pos,
                                                 int* __restrict__ srcs) {
    __shared__ short As[64][72];    // K-tile 64 + pad
    __shared__ short Bs[112][72];
    const int tid = threadIdx.x;

    if (blockIdx.x >= PROJ_BLOCKS) {
        int e = (blockIdx.x - PROJ_BLOCKS) * 256 + tid;
        if (e < E_EDGES) {
            int s = eidx[e];
            int d = eidx[E_EDGES + e];
            int p = atomicAdd(&pos[d], 1);
            srcs[offs[d] + p] = s;
        }
        return;
    }

    const int wave = tid >> 6, lane = tid & 63;
    const int row0 = blockIdx.x * 64;
    const int l15 = lane & 15, l4 = lane >> 4;

    f32x4 acc[7];
#pragma unroll
    for (int j = 0; j < 7; j++) acc[j] = (f32x4){0.f, 0.f, 0.f, 0.f};

    for (int k0 = 0; k0 < LLM_DIM; k0 += 64) {
        // A tile 64x64 fp32 -> bf16 LDS. 1024 float4, 4/thread, coalesced per row.
#pragma unroll
        for (int i = 0; i < 4; i++) {
            int f = i * 256 + tid;
            int r = f >> 4;          // 16 float4 per row
            int q = f & 15;
            int grow = row0 + r;
            float4 v = make_float4(0.f, 0.f, 0.f, 0.f);
            if (grow < N_NODES)
                v = *reinterpret_cast<const float4*>(A + (size_t)grow * LLM_DIM + k0 + q * 4);
            uint2 u;
            u.x = (unsigned)f2bf(v.x) | ((unsigned)f2bf(v.y) << 16);
            u.y = (unsigned)f2bf(v.z) | ((unsigned)f2bf(v.w) << 16);
            *reinterpret_cast<uint2*>(&As[r][q * 4]) = u;
        }
        // B tile 112x64 bf16. 1792 8B chunks, 7/thread.
#pragma unroll
        for (int i = 0; i < 7; i++) {
            int f = i * 256 + tid;
            int n = f >> 4;
            int q = f & 15;
            uint2 v = *reinterpret_cast<const uint2*>(Wt + (size_t)n * LLM_DIM + k0 + q * 4);
            *reinterpret_cast<uint2*>(&Bs[n][q * 4]) = v;
        }
        __syncthreads();
#pragma unroll
        for (int ks = 0; ks < 2; ks++) {
            int kk = ks * 32 + l4 * 8;
            bf16x8 a = *reinterpret_cast<bf16x8*>(&As[wave * 16 + l15][kk]);
#pragma unroll
            for (int ct = 0; ct < 7; ct++) {
                bf16x8 b = *reinterpret_cast<bf16x8*>(&Bs[ct * 16 + l15][kk]);
                acc[ct] = __builtin_amdgcn_mfma_f32_16x16x32_bf16(a, b, acc[ct], 0, 0, 0);
            }
        }
        __syncthreads();
    }
    // epilogue: rows row0 + wave*16 + l4*4 + r; cols ct*16 + l15 (+ emb cols 112..127)
#pragma unroll
    for (int r = 0; r < 4; r++) {
        int row = row0 + wave * 16 + l4 * 4 + r;
        if (row >= N_NODES) continue;
        float d = dis[row];
#pragma unroll
        for (int ct = 0; ct < 7; ct++) {
            int col = ct * 16 + l15;
            Xs[(size_t)row * HIDDEN + col] = f2bf(d * (acc[ct][r] + bias[col]));
        }
        float e = emb[sid[row] * 16 + l15];
        Xs[(size_t)row * HIDDEN + POUT + l15] = f2bf(d * e);
    }
}

// ---------------- CSR gather on bf16: Gb[i] = bf16(dis_i*(sum Xs[src] + Xs[i])) (proven) ----------------
__global__ __launch_bounds__(256) void gather(const unsigned short* __restrict__ Xs,
                                              const int* __restrict__ offs,
                                              const int* __restrict__ srcs,
                                              const float* __restrict__ dis,
                                              unsigned short* __restrict__ Gb) {
    int node = blockIdx.x * 4 + (threadIdx.x >> 6);
    int lane = threadIdx.x & 63;
    if (node >= N_NODES) return;
    int beg = __builtin_amdgcn_readfirstlane(offs[node]);
    int end = __builtin_amdgcn_readfirstlane(offs[node + 1]);
    const unsigned* X32 = reinterpret_cast<const unsigned*>(Xs);
    float d = dis[node];
    unsigned sv = X32[(size_t)node * 64 + lane];
    float ax = 0.f, ay = 0.f;
    int e = beg;
    while (e < end) {
        int n = end - e;
        if (n > 64) n = 64;
        int idx = (lane < n) ? srcs[e + lane] : 0;
        int j = 0;
        for (; j + 8 <= n; j += 8) {
            int s0 = __shfl(idx, j);
            int s1 = __shfl(idx, j + 1);
            int s2 = __shfl(idx, j + 2);
            int s3 = __shfl(idx, j + 3);
            int s4 = __shfl(idx, j + 4);
            int s5 = __shfl(idx, j + 5);
            int s6 = __shfl(idx, j + 6);
            int s7 = __shfl(idx, j + 7);
            unsigned v0 = X32[(size_t)s0 * 64 + lane];
            unsigned v1 = X32[(size_t)s1 * 64 + lane];
            unsigned v2 = X32[(size_t)s2 * 64 + lane];
            unsigned v3 = X32[(size_t)s3 * 64 + lane];
            unsigned v4 = X32[(size_t)s4 * 64 + lane];
            unsigned v5 = X32[(size_t)s5 * 64 + lane];
            unsigned v6 = X32[(size_t)s6 * 64 + lane];
            unsigned v7 = X32[(size_t)s7 * 64 + lane];
            ax += ((bflo(v0) + bflo(v1)) + (bflo(v2) + bflo(v3)))
                + ((bflo(v4) + bflo(v5)) + (bflo(v6) + bflo(v7)));
            ay += ((bfhi(v0) + bfhi(v1)) + (bfhi(v2) + bfhi(v3)))
                + ((bfhi(v4) + bfhi(v5)) + (bfhi(v6) + bfhi(v7)));
        }
        if (j + 4 <= n) {
            int s0 = __shfl(idx, j);
            int s1 = __shfl(idx, j + 1);
            int s2 = __shfl(idx, j + 2);
            int s3 = __shfl(idx, j + 3);
            unsigned v0 = X32[(size_t)s0 * 64 + lane];
            unsigned v1 = X32[(size_t)s1 * 64 + lane];
            unsigned v2 = X32[(size_t)s2 * 64 + lane];
            unsigned v3 = X32[(size_t)s3 * 64 + lane];
            ax += (bflo(v0) + bflo(v1)) + (bflo(v2) + bflo(v3));
            ay += (bfhi(v0) + bfhi(v1)) + (bfhi(v2) + bfhi(v3));
            j += 4;
        }
        int rem = n - j;
        if (rem > 0) {
            int s0 = __shfl(idx, j);
            int s1 = __shfl(idx, j + (rem > 1 ? 1 : 0));
            int s2 = __shfl(idx, j + (rem > 2 ? 2 : 0));
            unsigned v0 = X32[(size_t)s0 * 64 + lane];
            unsigned v1 = X32[(size_t)s1 * 64 + lane];
            unsigned v2 = X32[(size_t)s2 * 64 + lane];
            ax += bflo(v0) + (rem > 1 ? bflo(v1) : 0.f) + (rem > 2 ? bflo(v2) : 0.f);
            ay += bfhi(v0) + (rem > 1 ? bfhi(v1) : 0.f) + (rem > 2 ? bfhi(v2) : 0.f);
        }
        e += 64;
    }
    ax = d * (ax + bflo(sv));   // self term = dis_i * Xs_i
    ay = d * (ay + bfhi(sv));
    reinterpret_cast<unsigned*>(Gb)[(size_t)node * 64 + lane] =
        (unsigned)f2bf(ax) | ((unsigned)f2bf(ay) << 16);
}

// ---------------- fused GEMM + residual(+relu) in SCALED space (r10 proven) ----------------
// State carried only in Xs = bf16(d*x). vs = Xs + d*relu(Gb@W + b) == d*x_new (exact).
// MODE 0: XsOut = f2bf(vs). MODE 1: X = LayerNorm(vs, eps' = eps*d^2) == LN(x_new) exactly.
template <int MODE>
__global__ __launch_bounds__(256) void gemm_fin(const unsigned short* __restrict__ Gb,
                                                const unsigned short* __restrict__ Wt2,
                                                const float* __restrict__ bias,
                                                const float* __restrict__ dis,
                                                const float* __restrict__ lng,
                                                const float* __restrict__ lnb,
                                                const unsigned short* XsIn,
                                                float* __restrict__ X,
                                                unsigned short* XsOut) {
    __shared__ short As[64][136];    // K=128 + 8 pad
    __shared__ short Bs[128][136];
    const int tid = threadIdx.x;
    const int wave = tid >> 6, lane = tid & 63;
    const int row0 = blockIdx.x * 64;
    const int l15 = lane & 15, l4 = lane >> 4;

    // stage A 64x128 bf16: 1024 uint4, 4/thread
#pragma unroll
    for (int i = 0; i < 4; i++) {
        int f = i * 256 + tid;
        int r = f >> 4;
        int q = f & 15;
        int grow = row0 + r;
        uint4 v = make_uint4(0, 0, 0, 0);
        if (grow < N_NODES)
            v = reinterpret_cast<const uint4*>(Gb + (size_t)grow * HIDDEN)[q];
        *reinterpret_cast<uint4*>(&As[r][q * 8]) = v;
    }
    // stage B 128x128 bf16: 2048 uint4, 8/thread
#pragma unroll
    for (int i = 0; i < 8; i++) {
        int f = i * 256 + tid;
        int r = f >> 4;
        int q = f & 15;
        uint4 v = reinterpret_cast<const uint4*>(Wt2 + (size_t)r * HIDDEN)[q];
        *reinterpret_cast<uint4*>(&Bs[r][q * 8]) = v;
    }

    // hoisted residual (scaled space) + per-row dis; overlaps barrier + MFMA
    const unsigned* XsU = reinterpret_cast<const unsigned*>(XsIn);
    float xs[8][4];
    float dv[4];
#pragma unroll
    for (int r = 0; r < 4; r++) {
        int row = row0 + wave * 16 + l4 * 4 + r;
        int rc = row < N_NODES ? row : 0;
        dv[r] = dis[rc];
        bool hi = (l15 & 1) != 0;
#pragma unroll
        for (int ct = 0; ct < 8; ct++) {
            unsigned u = XsU[(size_t)rc * 64 + ct * 8 + (l15 >> 1)];
            xs[ct][r] = hi ? bfhi(u) : bflo(u);
        }
    }

    __syncthreads();

    f32x4 acc[8];
#pragma unroll
    for (int j = 0; j < 8; j++) acc[j] = (f32x4){0.f, 0.f, 0.f, 0.f};
#pragma unroll
    for (int ks = 0; ks < 4; ks++) {
        int kk = ks * 32 + l4 * 8;
        bf16x8 a = *reinterpret_cast<bf16x8*>(&As[wave * 16 + l15][kk]);
#pragma unroll
        for (int ct = 0; ct < 8; ct++) {
            bf16x8 b = *reinterpret_cast<bf16x8*>(&Bs[ct * 16 + l15][kk]);
            acc[ct] = __builtin_amdgcn_mfma_f32_16x16x32_bf16(a, b, acc[ct], 0, 0, 0);
        }
    }

    // epilogue: vs = xs + d*relu(acc + bias)   (== d * x_new, exact)
    float bcol[8];
#pragma unroll
    for (int ct = 0; ct < 8; ct++) bcol[ct] = bias[ct * 16 + l15];

    float vv[8][4];
#pragma unroll
    for (int r = 0; r < 4; r++) {
#pragma unroll
        for (int ct = 0; ct < 8; ct++)
            vv[ct][r] = xs[ct][r] + dv[r] * fmaxf(acc[ct][r] + bcol[ct], 0.f);
    }

    if (MODE == 0) {
#pragma unroll
        for (int r = 0; r < 4; r++) {
            int row = row0 + wave * 16 + l4 * 4 + r;
            if (row >= N_NODES) continue;
#pragma unroll
            for (int ct = 0; ct < 8; ct++)
                XsOut[(size_t)row * HIDDEN + ct * 16 + l15] = f2bf(vv[ct][r]);
        }
    } else {
        float s[4], q2[4];
#pragma unroll
        for (int r = 0; r < 4; r++) {
            s[r] = 0.f; q2[r] = 0.f;
#pragma unroll
            for (int ct = 0; ct < 8; ct++) {
                s[r] += vv[ct][r];
                q2[r] += vv[ct][r] * vv[ct][r];
            }
        }
#pragma unroll
        for (int off = 1; off < 16; off <<= 1) {
#pragma unroll
            for (int r = 0; r < 4; r++) {
                s[r] += __shfl_xor(s[r], off);
                q2[r] += __shfl_xor(q2[r], off);
            }
        }
        float gcol[8], bcol2[8];
#pragma unroll
        for (int ct = 0; ct < 8; ct++) {
            gcol[ct] = lng[ct * 16 + l15];
            bcol2[ct] = lnb[ct * 16 + l15];
        }
#pragma unroll
        for (int r = 0; r < 4; r++) {
            int row = row0 + wave * 16 + l4 * 4 + r;
            if (row >= N_NODES) continue;
            float mean = s[r] * (1.f / 128.f);
            float var = q2[r] * (1.f / 128.f) - mean * mean;
            float inv = rsqrtf(var + 1e-5f * dv[r] * dv[r]);   // eps scaled: LN exact in scaled space
#pragma unroll
            for (int ct = 0; ct < 8; ct++) {
                int col = ct * 16 + l15;
                X[(size_t)row * HIDDEN + col] = (vv[ct][r] - mean) * inv * gcol[ct] + bcol2[ct];
            }
        }
    }
}

extern "C" void kernel_launch(void* const* d_in, const int* in_sizes, int n_in,
                              void* d_out, int out_size, void* d_ws, size_t ws_size,
                              hipStream_t stream) {
    const float* llm   = (const float*)d_in[0];
    const int*   sid   = (const int*)d_in[1];
    const int*   eidx  = (const int*)d_in[2];
    const float* projW = (const float*)d_in[3];
    const float* projb = (const float*)d_in[4];
    const float* emb   = (const float*)d_in[5];
    const float* gcnW  = (const float*)d_in[6];
    const float* gcnb  = (const float*)d_in[7];
    const float* lng   = (const float*)d_in[8];
    const float* lnb   = (const float*)d_in[9];

    float* X = (float*)d_out;                                   // [N,128] fp32 (final only)
    unsigned short* Xs = (unsigned short*)d_ws;                 // [N,128] bf16 (running scaled state)
    unsigned short* Gb = Xs + (size_t)N_NODES * HIDDEN;         // [N,128] bf16
    unsigned short* Wt = Gb;                                    // [112,640] bf16 (overlaps Gb: dead before gather)
    unsigned short* Wt2 = Gb + (size_t)N_NODES * HIDDEN;        // [2,128,128] bf16
    float* dis = (float*)(Wt2 + 2 * HIDDEN * HIDDEN);           // [N]
    int* cnt  = (int*)(dis + N_NODES);                          // [N]
    int* pos  = cnt + N_NODES;                                  // [N] (zeroed in deg_conv tail blocks)
    int* offs = pos + N_NODES;                                  // [N+1]
    int* bsum = offs + N_NODES + 1;                             // [128]
    int* bpre = bsum + 128;                                     // [128] (unused; layout stability)
    int* srcs = bpre + 128;                                     // [E]

    hipMemsetAsync(cnt, 0, N_NODES * sizeof(int), stream);      // cnt only (pos zeroed in deg_conv)
    deg_conv<<<FILL_BLOCKS + CONV_BLOCKS + PZ_BLOCKS, 256, 0, stream>>>(eidx, cnt, projW, gcnW,
                                                                        Wt, Wt2, pos);
    scan_blocksum<<<NB_SCAN, 256, 0, stream>>>(cnt, bsum, dis); // + fused make_dis
    scan_offs<<<NB_SCAN, 256, 0, stream>>>(cnt, bsum, offs);    // + in-kernel base (scan_bsum folded)

    // proj blocks FIRST (occupy CUs at t=0), fill blocks after (overlap in spare resident slots)
    proj_fill<<<PROJ_BLOCKS + FILL_BLOCKS, 256, 0, stream>>>(llm, Wt, projb, emb, sid, dis, Xs,
                                                             eidx, offs, pos, srcs);

    gather<<<(N_NODES + 3) / 4, 256, 0, stream>>>(Xs, offs, srcs, dis, Gb);
    gemm_fin<0><<<(N_NODES + 63) / 64, 256, 0, stream>>>(Gb, Wt2, gcnb, dis, lng, lnb, Xs, X, Xs);
    gather<<<(N_NODES + 3) / 4, 256, 0, stream>>>(Xs, offs, srcs, dis, Gb);
    gemm_fin<1><<<(N_NODES + 63) / 64, 256, 0, stream>>>(Gb, Wt2 + HIDDEN * HIDDEN, gcnb + HIDDEN,
                                                         dis, lng, lnb, Xs, X, Xs);
}